// Round 8
// baseline (193.747 us; speedup 1.0000x reference)
//
#include <hip/hip_runtime.h>
#include <stdint.h>

// y[b,s,m] = sum_n x[b,s,n] * W[m,n] + bias[m], W from TT cores (bf16, built once).
// Pipeline: prep (build_w + convert_x fused) -> 8-phase 256^2 GEMM, 32x32x16 MFMA
// in NORMAL orientation (A=X first, B=W second) so the C/D layout is exactly the
// HW-verified m74/m101 mapping: row(M)=(r&3)+8*(r>>2)+4*(lane>>5), col(N)=lane&31.
// Staging/swizzle/vmcnt/B-reg-ping-pong identical to the verified round-6 kernel.

typedef __attribute__((ext_vector_type(8))) __bf16 bf16x8;
typedef __attribute__((ext_vector_type(4))) float f32x4;
typedef __attribute__((ext_vector_type(16))) float f32x16;
typedef __attribute__((ext_vector_type(4))) unsigned short us4;
typedef __attribute__((ext_vector_type(8))) unsigned short us8;

#define M_TOT 16384
#define N_TOT 2048
#define K_TOT 2048

__device__ __forceinline__ unsigned short f2bf(float f) {
  union { float f; unsigned u; } v; v.f = f;
  unsigned u = v.u;
  u += 0x7FFFu + ((u >> 16) & 1u);   // RNE
  return (unsigned short)(u >> 16);
}

__device__ __forceinline__ void gld_lds16(const void* g, void* l) {
  __builtin_amdgcn_global_load_lds(
      (const __attribute__((address_space(1))) unsigned int*)g,
      (__attribute__((address_space(3))) unsigned int*)l, 16, 0, 0);
}

#define BARRIER() __builtin_amdgcn_s_barrier()
#define WAIT_LGKM0() asm volatile("s_waitcnt lgkmcnt(0)" ::: "memory")
#define WAIT_VM(N) asm volatile("s_waitcnt vmcnt(" #N ")" ::: "memory")

// ---------------------------------------------------------------------------
// Kernel 1: fused prep. Blocks [0,nconv): X fp32->bf16 (1 us8/thread);
// blocks [nconv, nconv+16384): build W bf16 from TT cores.
// ---------------------------------------------------------------------------
__global__ void prep_kernel(const float* __restrict__ X,
                            unsigned short* __restrict__ Xb,
                            const float* __restrict__ c1,
                            const float* __restrict__ c2,
                            unsigned short* __restrict__ W,
                            int nconv) {
  const int bid = blockIdx.x;
  if (bid < nconv) {
    const size_t i = (size_t)bid * 256 + threadIdx.x;   // us8 index
    f32x4 a = ((const f32x4*)X)[i * 2];
    f32x4 b = ((const f32x4*)X)[i * 2 + 1];
    us8 h;
    h[0] = f2bf(a[0]); h[1] = f2bf(a[1]); h[2] = f2bf(a[2]); h[3] = f2bf(a[3]);
    h[4] = f2bf(b[0]); h[5] = f2bf(b[1]); h[6] = f2bf(b[2]); h[7] = f2bf(b[3]);
    ((us8*)Xb)[i] = h;
  } else {
    int idx = (bid - nconv) * 256 + threadIdx.x;   // n*2048 + k
    int k = idx & (K_TOT - 1);
    int n = idx >> 11;
    int i = n >> 9, ob = n & 511;
    int m1 = ob >> 4, m2 = ob & 15;
    int j = k >> 9, ib = k & 511;
    int n1 = ib >> 4, n2 = ib & 15;
    const float* a = c1 + ((((i * 4 + j) * 32 + m1) * 32 + n1) * 16);
    const float* b = c2 + ((i * 4 + j) * 4096 + m2 * 16 + n2);
    float s = 0.f;
#pragma unroll
    for (int r = 0; r < 16; ++r) s += a[r] * b[r * 256];
    W[idx] = f2bf(s);
  }
}

// ---------------------------------------------------------------------------
// Kernel 2: 8-phase 256x256 bf16 GEMM, BK=64, 512 thr (8 waves 2Mx4N),
// v_mfma_f32_32x32x16_bf16 (normal orientation). LDS 128 KiB:
// [buf2][sect4][128x64 bf16]; sect 0/1 = A halves, 2/3 = B halves.
// Phase q computes M-rep q (32 rows x 64 cols x K=64: 8 MFMA, 2 chains of 4).
// XOR swizzle both-sides; counted vmcnt (never 0 mid-loop); B frags reg-pipelined.
// ---------------------------------------------------------------------------
__global__ __launch_bounds__(512, 2) void gemm8p_kernel(
    const unsigned short* __restrict__ Xb, const unsigned short* __restrict__ W,
    const float* __restrict__ bias, float* __restrict__ Y) {
  __shared__ __align__(16) unsigned short lds[2][4][128 * 64];

  const int tid = threadIdx.x;
  const int lane = tid & 63;
  const int wid = tid >> 6;
  const int wm = wid >> 2, wn = wid & 3;     // 2 x 4 wave grid

  const int bid = blockIdx.x;
  const int xcd = bid & 7, loc = bid >> 3;
  const int mblk = xcd * 8 + (loc >> 3);     // 0..63
  const int nblk = loc & 7;                  // 0..7
  const int m0 = mblk * 256, n0 = nblk * 256;

  // 32x32x16 fragment addressing: free index = lane&31, k-half = lane>>5
  const int l31 = lane & 31, g5 = lane >> 5;
  const int swzl = lane & 7;                 // == row&7 for all our frag rows
  int blkoff[4];                             // 16B-block byte offset per k-rep
#pragma unroll
  for (int kr = 0; kr < 4; ++kr) blkoff[kr] = ((kr * 2 + g5) ^ swzl) * 16;
  const int arowB = l31 * 128;                       // + mr*4096 bytes
  const int browB = ((wn & 1) * 64 + l31) * 128;     // + nr*4096 bytes

  // staging: both-sides swizzle (block b of row r stored at b^(r&7))
  const int sr = tid >> 3;
  const int sc = ((tid & 7) ^ (sr & 7)) * 8;

  auto stageA = [&](int half, int buf, int kt) {
    const unsigned short* base = Xb + (size_t)(m0 + half * 128) * K_TOT + kt * 64 + sc;
#pragma unroll
    for (int i = 0; i < 2; ++i)
      gld_lds16(base + (size_t)(i * 64 + sr) * K_TOT,
                &lds[buf][half][i * 4096 + wid * 512]);
  };
  auto stageB = [&](int half, int buf, int kt) {
    const unsigned short* base = W + (size_t)(n0 + half * 128) * K_TOT + kt * 64 + sc;
#pragma unroll
    for (int i = 0; i < 2; ++i)
      gld_lds16(base + (size_t)(i * 64 + sr) * K_TOT,
                &lds[buf][2 + half][i * 4096 + wid * 512]);
  };
  auto ldA = [&](int c, int mr, int kr) -> bf16x8 {
    const char* p = (const char*)&lds[c][wm][0] + arowB + mr * 4096 + blkoff[kr];
    return *(const bf16x8*)p;
  };
  auto ldB = [&](int c, int nr, int kr) -> bf16x8 {
    const char* p = (const char*)&lds[c][2 + (wn >> 1)][0] + browB + nr * 4096 + blkoff[kr];
    return *(const bf16x8*)p;
  };

  f32x16 acc[4][2];
#pragma unroll
  for (int m = 0; m < 4; ++m)
#pragma unroll
    for (int n = 0; n < 2; ++n) acc[m][n] = (f32x16)(0.f);

  const int NT = K_TOT / 64;  // 32 K-tiles (even)

  // prologue: tile0 (A+B) -> buf0, B of tile1 -> buf1
  stageA(0, 0, 0); stageA(1, 0, 0);       // 4 loads
  stageB(0, 0, 0); stageB(1, 0, 0);       // 4
  stageB(0, 1, 1); stageB(1, 1, 1);       // 4 (tile1 B)
  WAIT_VM(4);                             // tile0 landed; B(1) in flight
  BARRIER();

  bf16x8 bqX[2][4], bqY[2][4];            // [nrep][krep]
#pragma unroll
  for (int nr = 0; nr < 2; ++nr)
#pragma unroll
    for (int kr = 0; kr < 4; ++kr) bqX[nr][kr] = ldB(0, nr, kr);

  auto body = [&](int t, int c, bf16x8 (&bqc)[2][4], bf16x8 (&bqn)[2][4]) {
#pragma unroll
    for (int q = 0; q < 4; ++q) {          // q = M-rep
      bf16x8 a0 = ldA(c, q, 0);
      bf16x8 a1 = ldA(c, q, 1);
      bf16x8 a2 = ldA(c, q, 2);
      bf16x8 a3 = ldA(c, q, 3);
      if (q == 0 && t + 1 < NT) stageA(0, c ^ 1, t + 1);
      if (q == 1) {
        if (t + 1 < NT) {
          stageA(1, c ^ 1, t + 1);
          WAIT_VM(4);                      // B(t+1) landed (A(t+1) in flight)
          bqn[0][0] = ldB(c ^ 1, 0, 0); bqn[0][1] = ldB(c ^ 1, 0, 1);
          bqn[0][2] = ldB(c ^ 1, 0, 2); bqn[0][3] = ldB(c ^ 1, 0, 3);
        }
      }
      if (q == 2) {
        if (t + 2 < NT) stageB(0, c, t + 2);
        if (t + 1 < NT) {
          bqn[1][0] = ldB(c ^ 1, 1, 0); bqn[1][1] = ldB(c ^ 1, 1, 1);
          bqn[1][2] = ldB(c ^ 1, 1, 2); bqn[1][3] = ldB(c ^ 1, 1, 3);
        }
      }
      if (q == 3) {
        if (t + 2 < NT) { stageB(1, c, t + 2); WAIT_VM(4); }  // A(t+1) landed
        else            { WAIT_VM(0); }                        // tail drain
      }
      BARRIER();
      WAIT_LGKM0();
      __builtin_amdgcn_s_setprio(1);
#pragma unroll
      for (int kr = 0; kr < 4; ++kr) {
        bf16x8 ak = (kr == 0) ? a0 : (kr == 1) ? a1 : (kr == 2) ? a2 : a3;
        acc[q][0] = __builtin_amdgcn_mfma_f32_32x32x16_bf16(ak, bqc[0][kr], acc[q][0], 0, 0, 0);
        acc[q][1] = __builtin_amdgcn_mfma_f32_32x32x16_bf16(ak, bqc[1][kr], acc[q][1], 0, 0, 0);
      }
      __builtin_amdgcn_s_setprio(0);
      BARRIER();
    }
  };

  for (int tt = 0; tt < NT; tt += 2) {
    body(tt,     0, bqX, bqY);   // uses bqX, prefetches tile tt+1 B -> bqY
    body(tt + 1, 1, bqY, bqX);   // uses bqY, prefetches tile tt+2 B -> bqX
  }

  // epilogue: NORMAL-orientation D (m74/m101-verified):
  //   M-row = (r&3) + 8*(r>>2) + 4*g5   (within the 32-row M-rep)
  //   N-col = lane&31                   (within the 32-col N-rep)
  // Lanes 0..31 of a store cover 32 consecutive cols of one row (128B seg).
  const float bv0 = bias[n0 + wn * 64 + 0  + l31];
  const float bv1 = bias[n0 + wn * 64 + 32 + l31];
#pragma unroll
  for (int mr = 0; mr < 4; ++mr) {
#pragma unroll
    for (int nr = 0; nr < 2; ++nr) {
      const int gc = n0 + wn * 64 + nr * 32 + l31;
      const float bv = nr ? bv1 : bv0;
#pragma unroll
      for (int r = 0; r < 16; ++r) {
        const int gr = m0 + wm * 128 + mr * 32 + (r & 3) + 8 * (r >> 2) + 4 * g5;
        Y[(size_t)gr * N_TOT + gc] = acc[mr][nr][r] + bv;
      }
    }
  }
}

// ---------------------------------------------------------------------------
// Fallback GEMM (verified round 1): 128^2 tile, in-kernel fp32->bf16 A staging.
// ---------------------------------------------------------------------------
__global__ __launch_bounds__(256, 2) void gemm_fb_kernel(
    const float* __restrict__ X, const unsigned short* __restrict__ W,
    const float* __restrict__ bias, float* __restrict__ Y) {
  __shared__ __align__(16) unsigned short Alds[2][128 * 32];
  __shared__ __align__(16) unsigned short Blds[2][128 * 32];
  const int tid = threadIdx.x;
  const int lane = tid & 63;
  const int wid = tid >> 6;
  const int wm = wid >> 1, wn = wid & 1;
  int bid = blockIdx.x;
  int wgid = (bid & 7) * (2048 / 8) + (bid >> 3);
  const int m0 = (wgid >> 4) * 128, n0 = (wgid & 15) * 128;
  const int ar = tid >> 3, ac = (tid & 7) * 4;
  const int br = (tid >> 2), bc = (tid & 3) * 8;
  f32x4 acc[4][4];
#pragma unroll
  for (int m = 0; m < 4; ++m)
#pragma unroll
    for (int n = 0; n < 4; ++n) acc[m][n] = {0.f, 0.f, 0.f, 0.f};
  f32x4 apre[4];
  auto stA_l = [&](int k0) {
#pragma unroll
    for (int p = 0; p < 4; ++p)
      apre[p] = *(const f32x4*)&X[(size_t)(m0 + p * 32 + ar) * K_TOT + k0 + ac];
  };
  auto stA_w = [&](int buf) {
#pragma unroll
    for (int p = 0; p < 4; ++p) {
      us4 h;
      h[0] = f2bf(apre[p][0]); h[1] = f2bf(apre[p][1]);
      h[2] = f2bf(apre[p][2]); h[3] = f2bf(apre[p][3]);
      *(us4*)&Alds[buf][(p * 32 + ar) * 32 + ac] = h;
    }
  };
  auto stB = [&](int k0, int buf) {
#pragma unroll
    for (int i = 0; i < 2; ++i)
      gld_lds16(&W[(size_t)(n0 + i * 64 + br) * K_TOT + k0 + bc],
                &Blds[buf][i * 2048 + wid * 512]);
  };
  auto comp = [&](int buf) {
    const unsigned short* Ab = &Alds[buf][(wm * 64 + (lane & 15)) * 32 + (lane >> 4) * 8];
    const unsigned short* Bb = &Blds[buf][(wn * 64 + (lane & 15)) * 32 + (lane >> 4) * 8];
    bf16x8 af[4], bfv[4];
#pragma unroll
    for (int m = 0; m < 4; ++m) af[m] = *(const bf16x8*)(Ab + m * 16 * 32);
#pragma unroll
    for (int n = 0; n < 4; ++n) bfv[n] = *(const bf16x8*)(Bb + n * 16 * 32);
#pragma unroll
    for (int m = 0; m < 4; ++m)
#pragma unroll
      for (int n = 0; n < 4; ++n)
        acc[m][n] = __builtin_amdgcn_mfma_f32_16x16x32_bf16(af[m], bfv[n], acc[m][n], 0, 0, 0);
  };
  stA_l(0); stB(0, 0); stA_w(0);
  __syncthreads();
  for (int kt = 0; kt < 64; ++kt) {
    const int cur = kt & 1, nxt = cur ^ 1;
    if (kt + 1 < 64) { stA_l((kt + 1) * 32); stB((kt + 1) * 32, nxt); }
    comp(cur);
    if (kt + 1 < 64) stA_w(nxt);
    __syncthreads();
  }
  const int col = lane & 15, rb = (lane >> 4) * 4;
#pragma unroll
  for (int n = 0; n < 4; ++n) {
    const int gc = n0 + wn * 64 + n * 16 + col;
    const float bv = bias[gc];
#pragma unroll
    for (int m = 0; m < 4; ++m)
#pragma unroll
      for (int j = 0; j < 4; ++j)
        Y[(size_t)(m0 + wm * 64 + m * 16 + rb + j) * N_TOT + gc] = acc[m][n][j] + bv;
  }
}

extern "C" void kernel_launch(void* const* d_in, const int* in_sizes, int n_in,
                              void* d_out, int out_size, void* d_ws, size_t ws_size,
                              hipStream_t stream) {
  const float* x    = (const float*)d_in[0];
  const float* c1   = (const float*)d_in[1];
  const float* c2   = (const float*)d_in[2];
  const float* bias = (const float*)d_in[3];
  float* y          = (float*)d_out;
  unsigned short* W = (unsigned short*)d_ws;                        // 8 MB
  unsigned short* Xb = (unsigned short*)((char*)d_ws + (8u << 20)); // 64 MB

  const size_t need = (size_t)(8u << 20) + (size_t)M_TOT * K_TOT * 2;
  if (ws_size >= need) {
    prep_kernel<<<16384 + 16384, 256, 0, stream>>>(x, Xb, c1, c2, W, 16384);
    gemm8p_kernel<<<(M_TOT / 256) * (N_TOT / 256), 512, 0, stream>>>(Xb, W, bias, y);
  } else {
    prep_kernel<<<16384, 256, 0, stream>>>(x, nullptr, c1, c2, W, 0);  // W only
    gemm_fb_kernel<<<(M_TOT / 128) * (N_TOT / 128), 256, 0, stream>>>(x, W, bias, y);
  }
}

// Round 11
// 178.743 us; speedup vs baseline: 1.0839x; 1.0839x over previous
//
#include <hip/hip_runtime.h>
#include <stdint.h>

// y[b,s,m] = sum_n x[b,s,n] * W[m,n] + bias[m], W from TT cores (bf16, built once).
// Pipeline: prep (build_w + convert_x fused, one dispatch) -> 8-phase 256^2 GEMM.
// GEMM: A = bf16 X (pre-converted), B = bf16 W, both via global_load_lds.
// B fragments REGISTER-PIPELINED across tiles (ping/pong). RACE-FIX vs round 6:
// bqn (next-tile B) LDS reads moved from q1 to q2/q3 — every wave drains its
// own B(t+1) loads via vmcnt(4) at q1 BEFORE q1's pre-MFMA barrier, so after
// that barrier the data is published to all waves; q2/q3 reads are safe
// (drain -> barrier -> read, the same proof pattern as the verified round-5
// structure). Reading at q1 (round 6) raced with other waves' in-flight DMA.
// MFMA operands swapped (W-frag first) -> D transposed -> f32x4 coalesced stores.

typedef __attribute__((ext_vector_type(8))) __bf16 bf16x8;
typedef __attribute__((ext_vector_type(4))) float f32x4;
typedef __attribute__((ext_vector_type(4))) unsigned short us4;
typedef __attribute__((ext_vector_type(8))) unsigned short us8;

#define M_TOT 16384
#define N_TOT 2048
#define K_TOT 2048

__device__ __forceinline__ unsigned short f2bf(float f) {
  union { float f; unsigned u; } v; v.f = f;
  unsigned u = v.u;
  u += 0x7FFFu + ((u >> 16) & 1u);   // RNE
  return (unsigned short)(u >> 16);
}

__device__ __forceinline__ void gld_lds16(const void* g, void* l) {
  __builtin_amdgcn_global_load_lds(
      (const __attribute__((address_space(1))) unsigned int*)g,
      (__attribute__((address_space(3))) unsigned int*)l, 16, 0, 0);
}

#define BARRIER() __builtin_amdgcn_s_barrier()
#define WAIT_LGKM0() asm volatile("s_waitcnt lgkmcnt(0)" ::: "memory")
#define WAIT_VM(N) asm volatile("s_waitcnt vmcnt(" #N ")" ::: "memory")

// ---------------------------------------------------------------------------
// Kernel 1: fused prep. Blocks [0,nconv): X fp32->bf16 (1 us8/thread);
// blocks [nconv, nconv+16384): build W bf16 from TT cores.
// ---------------------------------------------------------------------------
__global__ void prep_kernel(const float* __restrict__ X,
                            unsigned short* __restrict__ Xb,
                            const float* __restrict__ c1,
                            const float* __restrict__ c2,
                            unsigned short* __restrict__ W,
                            int nconv) {
  const int bid = blockIdx.x;
  if (bid < nconv) {
    const size_t i = (size_t)bid * 256 + threadIdx.x;   // us8 index
    f32x4 a = ((const f32x4*)X)[i * 2];
    f32x4 b = ((const f32x4*)X)[i * 2 + 1];
    us8 h;
    h[0] = f2bf(a[0]); h[1] = f2bf(a[1]); h[2] = f2bf(a[2]); h[3] = f2bf(a[3]);
    h[4] = f2bf(b[0]); h[5] = f2bf(b[1]); h[6] = f2bf(b[2]); h[7] = f2bf(b[3]);
    ((us8*)Xb)[i] = h;
  } else {
    int idx = (bid - nconv) * 256 + threadIdx.x;   // n*2048 + k
    int k = idx & (K_TOT - 1);
    int n = idx >> 11;
    int i = n >> 9, ob = n & 511;
    int m1 = ob >> 4, m2 = ob & 15;
    int j = k >> 9, ib = k & 511;
    int n1 = ib >> 4, n2 = ib & 15;
    const float* a = c1 + ((((i * 4 + j) * 32 + m1) * 32 + n1) * 16);
    const float* b = c2 + ((i * 4 + j) * 4096 + m2 * 16 + n2);
    float s = 0.f;
#pragma unroll
    for (int r = 0; r < 16; ++r) s += a[r] * b[r * 256];
    W[idx] = f2bf(s);
  }
}

// ---------------------------------------------------------------------------
// Kernel 2: 8-phase 256x256 bf16 GEMM, BK=64, 512 thr (8 waves 2Mx4N).
// LDS 128 KiB: [buf2][sect4][128x64 bf16]; sect 0/1 = A halves, 2/3 = B halves.
// XOR swizzle both-sides (inverse-swizzled global source + swizzled ds_read).
// vmcnt chain: q1 WAIT(4) drains own B(t+1) (publication point for q2/q3
// reads); q3 WAIT(4) drains A(t+1); B(t+2) stays in flight. Never 0 mid-loop.
// ---------------------------------------------------------------------------
__global__ __launch_bounds__(512, 2) void gemm8p_kernel(
    const unsigned short* __restrict__ Xb, const unsigned short* __restrict__ W,
    const float* __restrict__ bias, float* __restrict__ Y) {
  __shared__ __align__(16) unsigned short lds[2][4][128 * 64];

  const int tid = threadIdx.x;
  const int lane = tid & 63;
  const int wid = tid >> 6;
  const int wm = wid >> 2, wn = wid & 3;     // 2 x 4 wave grid

  const int bid = blockIdx.x;
  const int xcd = bid & 7, loc = bid >> 3;
  const int mblk = xcd * 8 + (loc >> 3);     // 0..63
  const int nblk = loc & 7;                  // 0..7
  const int m0 = mblk * 256, n0 = nblk * 256;

  const int fr = lane & 15, g = lane >> 4;
  const int swz = fr & 7;
  const int blkB0 = ((0 + g) ^ swz) * 16;    // ksub=0 byte offset of 16B block
  const int blkB1 = ((4 + g) ^ swz) * 16;    // ksub=1
  const int arow = fr * 128;
  const int brow = ((wn & 1) * 64 + fr) * 128;

  const int sr = tid >> 3;
  const int sc = ((tid & 7) ^ (sr & 7)) * 8;

  auto stageA = [&](int half, int buf, int kt) {
    const unsigned short* base = Xb + (size_t)(m0 + half * 128) * K_TOT + kt * 64 + sc;
#pragma unroll
    for (int i = 0; i < 2; ++i)
      gld_lds16(base + (size_t)(i * 64 + sr) * K_TOT,
                &lds[buf][half][i * 4096 + wid * 512]);
  };
  auto stageB = [&](int half, int buf, int kt) {
    const unsigned short* base = W + (size_t)(n0 + half * 128) * K_TOT + kt * 64 + sc;
#pragma unroll
    for (int i = 0; i < 2; ++i)
      gld_lds16(base + (size_t)(i * 64 + sr) * K_TOT,
                &lds[buf][2 + half][i * 4096 + wid * 512]);
  };
  auto ldA = [&](int c, int m, int ks) -> bf16x8 {
    const char* p = (const char*)&lds[c][wm][0] + arow + m * 2048 + (ks ? blkB1 : blkB0);
    return *(const bf16x8*)p;
  };
  auto ldB = [&](int c, int n, int ks) -> bf16x8 {
    const char* p = (const char*)&lds[c][2 + (wn >> 1)][0] + brow + n * 2048 + (ks ? blkB1 : blkB0);
    return *(const bf16x8*)p;
  };

  f32x4 acc[8][4];
#pragma unroll
  for (int m = 0; m < 8; ++m)
#pragma unroll
    for (int n = 0; n < 4; ++n) acc[m][n] = {0.f, 0.f, 0.f, 0.f};

  const int NT = K_TOT / 64;  // 32 K-tiles (even)

  // prologue: tile0 (A+B) -> buf0, B of tile1 -> buf1
  stageA(0, 0, 0); stageA(1, 0, 0);       // 4 loads
  stageB(0, 0, 0); stageB(1, 0, 0);       // 4
  stageB(0, 1, 1); stageB(1, 1, 1);       // 4 (tile1 B)
  WAIT_VM(4);                             // A(0),B(0) landed; B(1) in flight
  BARRIER();                              // publish tile0 to all waves

  bf16x8 bqX[4][2], bqY[4][2];
  // tile0's B frags -> regs (post-barrier => safe; drained by first lgkmcnt(0))
#pragma unroll
  for (int n = 0; n < 4; ++n) {
    bqX[n][0] = ldB(0, n, 0);
    bqX[n][1] = ldB(0, n, 1);
  }

  auto body = [&](int t, int c, bf16x8 (&bqc)[4][2], bf16x8 (&bqn)[4][2]) {
#pragma unroll
    for (int q = 0; q < 4; ++q) {
      bf16x8 a0  = ldA(c, 2 * q, 0);
      bf16x8 a0k = ldA(c, 2 * q, 1);
      bf16x8 a1  = ldA(c, 2 * q + 1, 0);
      bf16x8 a1k = ldA(c, 2 * q + 1, 1);
      if (q == 0 && t + 1 < NT) stageA(0, c ^ 1, t + 1);
      if (q == 1 && t + 1 < NT) {
        stageA(1, c ^ 1, t + 1);
        WAIT_VM(4);    // drain own B(t+1); q1's pre-MFMA barrier publishes it
      }
      if (q == 2) {
        if (t + 2 < NT) stageB(0, c, t + 2);
        if (t + 1 < NT) {   // safe: all waves drained B(t+1) before q1 barrier
          bqn[0][0] = ldB(c ^ 1, 0, 0); bqn[0][1] = ldB(c ^ 1, 0, 1);
          bqn[1][0] = ldB(c ^ 1, 1, 0); bqn[1][1] = ldB(c ^ 1, 1, 1);
        }
      }
      if (q == 3) {
        if (t + 2 < NT) { stageB(1, c, t + 2); WAIT_VM(4); }  // A(t+1) landed
        else            { WAIT_VM(0); }                        // tail drain
        if (t + 1 < NT) {
          bqn[2][0] = ldB(c ^ 1, 2, 0); bqn[2][1] = ldB(c ^ 1, 2, 1);
          bqn[3][0] = ldB(c ^ 1, 3, 0); bqn[3][1] = ldB(c ^ 1, 3, 1);
        }
      }
      BARRIER();
      WAIT_LGKM0();
      __builtin_amdgcn_s_setprio(1);
#pragma unroll
      for (int n = 0; n < 4; ++n) {
        acc[2 * q][n]     = __builtin_amdgcn_mfma_f32_16x16x32_bf16(bqc[n][0], a0,  acc[2 * q][n],     0, 0, 0);
        acc[2 * q][n]     = __builtin_amdgcn_mfma_f32_16x16x32_bf16(bqc[n][1], a0k, acc[2 * q][n],     0, 0, 0);
        acc[2 * q + 1][n] = __builtin_amdgcn_mfma_f32_16x16x32_bf16(bqc[n][0], a1,  acc[2 * q + 1][n], 0, 0, 0);
        acc[2 * q + 1][n] = __builtin_amdgcn_mfma_f32_16x16x32_bf16(bqc[n][1], a1k, acc[2 * q + 1][n], 0, 0, 0);
      }
      __builtin_amdgcn_s_setprio(0);
      BARRIER();
    }
  };

  for (int tt = 0; tt < NT; tt += 2) {
    body(tt,     0, bqX, bqY);   // uses bqX, prefetches tile tt+1 B -> bqY
    body(tt + 1, 1, bqY, bqX);   // uses bqY, prefetches tile tt+2 B -> bqX
  }

  // epilogue (swapped-D layout, verified rounds 5/6): M-sub = fr, N-sub = g*4+j.
  f32x4 biasv[4];
#pragma unroll
  for (int n = 0; n < 4; ++n)
    biasv[n] = *(const f32x4*)&bias[n0 + wn * 64 + n * 16 + g * 4];
#pragma unroll
  for (int m = 0; m < 8; ++m) {
    float* rowp = Y + (size_t)(m0 + wm * 128 + m * 16 + fr) * N_TOT;
#pragma unroll
    for (int n = 0; n < 4; ++n) {
      f32x4 v = acc[m][n] + biasv[n];
      *(f32x4*)&rowp[n0 + wn * 64 + n * 16 + g * 4] = v;
    }
  }
}

// ---------------------------------------------------------------------------
// Fallback GEMM (verified round 1): 128^2 tile, in-kernel fp32->bf16 A staging.
// ---------------------------------------------------------------------------
__global__ __launch_bounds__(256, 2) void gemm_fb_kernel(
    const float* __restrict__ X, const unsigned short* __restrict__ W,
    const float* __restrict__ bias, float* __restrict__ Y) {
  __shared__ __align__(16) unsigned short Alds[2][128 * 32];
  __shared__ __align__(16) unsigned short Blds[2][128 * 32];
  const int tid = threadIdx.x;
  const int lane = tid & 63;
  const int wid = tid >> 6;
  const int wm = wid >> 1, wn = wid & 1;
  int bid = blockIdx.x;
  int wgid = (bid & 7) * (2048 / 8) + (bid >> 3);
  const int m0 = (wgid >> 4) * 128, n0 = (wgid & 15) * 128;
  const int ar = tid >> 3, ac = (tid & 7) * 4;
  const int br = (tid >> 2), bc = (tid & 3) * 8;
  f32x4 acc[4][4];
#pragma unroll
  for (int m = 0; m < 4; ++m)
#pragma unroll
    for (int n = 0; n < 4; ++n) acc[m][n] = {0.f, 0.f, 0.f, 0.f};
  f32x4 apre[4];
  auto stA_l = [&](int k0) {
#pragma unroll
    for (int p = 0; p < 4; ++p)
      apre[p] = *(const f32x4*)&X[(size_t)(m0 + p * 32 + ar) * K_TOT + k0 + ac];
  };
  auto stA_w = [&](int buf) {
#pragma unroll
    for (int p = 0; p < 4; ++p) {
      us4 h;
      h[0] = f2bf(apre[p][0]); h[1] = f2bf(apre[p][1]);
      h[2] = f2bf(apre[p][2]); h[3] = f2bf(apre[p][3]);
      *(us4*)&Alds[buf][(p * 32 + ar) * 32 + ac] = h;
    }
  };
  auto stB = [&](int k0, int buf) {
#pragma unroll
    for (int i = 0; i < 2; ++i)
      gld_lds16(&W[(size_t)(n0 + i * 64 + br) * K_TOT + k0 + bc],
                &Blds[buf][i * 2048 + wid * 512]);
  };
  auto comp = [&](int buf) {
    const unsigned short* Ab = &Alds[buf][(wm * 64 + (lane & 15)) * 32 + (lane >> 4) * 8];
    const unsigned short* Bb = &Blds[buf][(wn * 64 + (lane & 15)) * 32 + (lane >> 4) * 8];
    bf16x8 af[4], bfv[4];
#pragma unroll
    for (int m = 0; m < 4; ++m) af[m] = *(const bf16x8*)(Ab + m * 16 * 32);
#pragma unroll
    for (int n = 0; n < 4; ++n) bfv[n] = *(const bf16x8*)(Bb + n * 16 * 32);
#pragma unroll
    for (int m = 0; m < 4; ++m)
#pragma unroll
      for (int n = 0; n < 4; ++n)
        acc[m][n] = __builtin_amdgcn_mfma_f32_16x16x32_bf16(af[m], bfv[n], acc[m][n], 0, 0, 0);
  };
  stA_l(0); stB(0, 0); stA_w(0);
  __syncthreads();
  for (int kt = 0; kt < 64; ++kt) {
    const int cur = kt & 1, nxt = cur ^ 1;
    if (kt + 1 < 64) { stA_l((kt + 1) * 32); stB((kt + 1) * 32, nxt); }
    comp(cur);
    if (kt + 1 < 64) stA_w(nxt);
    __syncthreads();
  }
  const int col = lane & 15, rb = (lane >> 4) * 4;
#pragma unroll
  for (int n = 0; n < 4; ++n) {
    const int gc = n0 + wn * 64 + n * 16 + col;
    const float bv = bias[gc];
#pragma unroll
    for (int m = 0; m < 4; ++m)
#pragma unroll
      for (int j = 0; j < 4; ++j)
        Y[(size_t)(m0 + wm * 64 + m * 16 + rb + j) * N_TOT + gc] = acc[m][n][j] + bv;
  }
}

extern "C" void kernel_launch(void* const* d_in, const int* in_sizes, int n_in,
                              void* d_out, int out_size, void* d_ws, size_t ws_size,
                              hipStream_t stream) {
  const float* x    = (const float*)d_in[0];
  const float* c1   = (const float*)d_in[1];
  const float* c2   = (const float*)d_in[2];
  const float* bias = (const float*)d_in[3];
  float* y          = (float*)d_out;
  unsigned short* W = (unsigned short*)d_ws;                        // 8 MB
  unsigned short* Xb = (unsigned short*)((char*)d_ws + (8u << 20)); // 64 MB

  const size_t need = (size_t)(8u << 20) + (size_t)M_TOT * K_TOT * 2;
  if (ws_size >= need) {
    prep_kernel<<<16384 + 16384, 256, 0, stream>>>(x, Xb, c1, c2, W, 16384);
    gemm8p_kernel<<<(M_TOT / 256) * (N_TOT / 256), 512, 0, stream>>>(Xb, W, bias, y);
  } else {
    prep_kernel<<<16384, 256, 0, stream>>>(x, nullptr, c1, c2, W, 0);  // W only
    gemm_fb_kernel<<<(M_TOT / 128) * (N_TOT / 128), 256, 0, stream>>>(x, W, bias, y);
  }
}

// Round 12
// 177.805 us; speedup vs baseline: 1.0897x; 1.0053x over previous
//
#include <hip/hip_runtime.h>
#include <stdint.h>

// y[b,s,m] = sum_n x[b,s,n] * W[m,n] + bias[m], W from TT cores (bf16, built once).
// Pipeline: prep (build_w + convert_x fused, one dispatch) -> 8-phase 256^2 GEMM.
// GEMM: A = bf16 X (pre-converted), B = bf16 W, both via global_load_lds.
// Round-11 verified sync skeleton (barriers + counted vmcnt chain, race-proof:
// all cross-wave LDS reads happen after a barrier that follows every wave's
// own vmcnt drain of the producing DMA). THIS ROUND: frag ds_reads moved to
// the post-MFMA TAIL of the previous phase (same barrier interval ordering,
// publication proofs unchanged) so lgkmcnt(0) no longer eats ds_read latency;
// MFMA issue order ksub-outer -> 8 independent accs, no dependent pairs.
// MFMA operands swapped (W-frag first) -> D transposed -> f32x4 coalesced stores.

typedef __attribute__((ext_vector_type(8))) __bf16 bf16x8;
typedef __attribute__((ext_vector_type(4))) float f32x4;
typedef __attribute__((ext_vector_type(4))) unsigned short us4;
typedef __attribute__((ext_vector_type(8))) unsigned short us8;

#define M_TOT 16384
#define N_TOT 2048
#define K_TOT 2048

__device__ __forceinline__ unsigned short f2bf(float f) {
  union { float f; unsigned u; } v; v.f = f;
  unsigned u = v.u;
  u += 0x7FFFu + ((u >> 16) & 1u);   // RNE
  return (unsigned short)(u >> 16);
}

__device__ __forceinline__ void gld_lds16(const void* g, void* l) {
  __builtin_amdgcn_global_load_lds(
      (const __attribute__((address_space(1))) unsigned int*)g,
      (__attribute__((address_space(3))) unsigned int*)l, 16, 0, 0);
}

#define BARRIER() __builtin_amdgcn_s_barrier()
#define WAIT_LGKM0() asm volatile("s_waitcnt lgkmcnt(0)" ::: "memory")
#define WAIT_VM(N) asm volatile("s_waitcnt vmcnt(" #N ")" ::: "memory")

// ---------------------------------------------------------------------------
// Kernel 1: fused prep. Blocks [0,nconv): X fp32->bf16 (1 us8/thread);
// blocks [nconv, nconv+16384): build W bf16 from TT cores.
// ---------------------------------------------------------------------------
__global__ void prep_kernel(const float* __restrict__ X,
                            unsigned short* __restrict__ Xb,
                            const float* __restrict__ c1,
                            const float* __restrict__ c2,
                            unsigned short* __restrict__ W,
                            int nconv) {
  const int bid = blockIdx.x;
  if (bid < nconv) {
    const size_t i = (size_t)bid * 256 + threadIdx.x;   // us8 index
    f32x4 a = ((const f32x4*)X)[i * 2];
    f32x4 b = ((const f32x4*)X)[i * 2 + 1];
    us8 h;
    h[0] = f2bf(a[0]); h[1] = f2bf(a[1]); h[2] = f2bf(a[2]); h[3] = f2bf(a[3]);
    h[4] = f2bf(b[0]); h[5] = f2bf(b[1]); h[6] = f2bf(b[2]); h[7] = f2bf(b[3]);
    ((us8*)Xb)[i] = h;
  } else {
    int idx = (bid - nconv) * 256 + threadIdx.x;   // n*2048 + k
    int k = idx & (K_TOT - 1);
    int n = idx >> 11;
    int i = n >> 9, ob = n & 511;
    int m1 = ob >> 4, m2 = ob & 15;
    int j = k >> 9, ib = k & 511;
    int n1 = ib >> 4, n2 = ib & 15;
    const float* a = c1 + ((((i * 4 + j) * 32 + m1) * 32 + n1) * 16);
    const float* b = c2 + ((i * 4 + j) * 4096 + m2 * 16 + n2);
    float s = 0.f;
#pragma unroll
    for (int r = 0; r < 16; ++r) s += a[r] * b[r * 256];
    W[idx] = f2bf(s);
  }
}

// ---------------------------------------------------------------------------
// Kernel 2: 8-phase 256x256 bf16 GEMM, BK=64, 512 thr (8 waves 2Mx4N).
// LDS 128 KiB: [buf2][sect4][128x64 bf16]; sect 0/1 = A halves, 2/3 = B halves.
// XOR swizzle both-sides. vmcnt chain: q1 WAIT(4) drains own B(t+1) (publication
// point for q2/q3-tail reads); q3 WAIT(4) drains A(t+1) (publication point for
// q3-tail next-tile A reads). Never 0 mid-loop.
// ---------------------------------------------------------------------------
__global__ __launch_bounds__(512, 2) void gemm8p_kernel(
    const unsigned short* __restrict__ Xb, const unsigned short* __restrict__ W,
    const float* __restrict__ bias, float* __restrict__ Y) {
  __shared__ __align__(16) unsigned short lds[2][4][128 * 64];

  const int tid = threadIdx.x;
  const int lane = tid & 63;
  const int wid = tid >> 6;
  const int wm = wid >> 2, wn = wid & 3;     // 2 x 4 wave grid

  const int bid = blockIdx.x;
  const int xcd = bid & 7, loc = bid >> 3;
  const int mblk = xcd * 8 + (loc >> 3);     // 0..63
  const int nblk = loc & 7;                  // 0..7
  const int m0 = mblk * 256, n0 = nblk * 256;

  const int fr = lane & 15, g = lane >> 4;
  const int swz = fr & 7;
  const int blkB0 = ((0 + g) ^ swz) * 16;    // ksub=0 byte offset of 16B block
  const int blkB1 = ((4 + g) ^ swz) * 16;    // ksub=1
  const int arow = fr * 128;
  const int brow = ((wn & 1) * 64 + fr) * 128;

  const int sr = tid >> 3;
  const int sc = ((tid & 7) ^ (sr & 7)) * 8;

  auto stageA = [&](int half, int buf, int kt) {
    const unsigned short* base = Xb + (size_t)(m0 + half * 128) * K_TOT + kt * 64 + sc;
#pragma unroll
    for (int i = 0; i < 2; ++i)
      gld_lds16(base + (size_t)(i * 64 + sr) * K_TOT,
                &lds[buf][half][i * 4096 + wid * 512]);
  };
  auto stageB = [&](int half, int buf, int kt) {
    const unsigned short* base = W + (size_t)(n0 + half * 128) * K_TOT + kt * 64 + sc;
#pragma unroll
    for (int i = 0; i < 2; ++i)
      gld_lds16(base + (size_t)(i * 64 + sr) * K_TOT,
                &lds[buf][2 + half][i * 4096 + wid * 512]);
  };
  auto ldA = [&](int c, int m, int ks) -> bf16x8 {
    const char* p = (const char*)&lds[c][wm][0] + arow + m * 2048 + (ks ? blkB1 : blkB0);
    return *(const bf16x8*)p;
  };
  auto ldB = [&](int c, int n, int ks) -> bf16x8 {
    const char* p = (const char*)&lds[c][2 + (wn >> 1)][0] + brow + n * 2048 + (ks ? blkB1 : blkB0);
    return *(const bf16x8*)p;
  };

  f32x4 acc[8][4];
#pragma unroll
  for (int m = 0; m < 8; ++m)
#pragma unroll
    for (int n = 0; n < 4; ++n) acc[m][n] = {0.f, 0.f, 0.f, 0.f};

  const int NT = K_TOT / 64;  // 32 K-tiles (even)

  // prologue: tile0 (A+B) -> buf0, B of tile1 -> buf1
  stageA(0, 0, 0); stageA(1, 0, 0);       // 4 loads
  stageB(0, 0, 0); stageB(1, 0, 0);       // 4
  stageB(0, 1, 1); stageB(1, 1, 1);       // 4 (tile1 B)
  WAIT_VM(4);                             // A(0),B(0) landed; B(1) in flight
  BARRIER();                              // publish tile0 to all waves

  bf16x8 bqX[4][2], bqY[4][2];
  bf16x8 fa0, fa1, fa2, fa3;              // current phase's A frags (SSA-renamed)
  // tile0 B frags + tile0 q0 A frags (post-barrier => safe; drained by first lgkmcnt(0))
#pragma unroll
  for (int n = 0; n < 4; ++n) {
    bqX[n][0] = ldB(0, n, 0);
    bqX[n][1] = ldB(0, n, 1);
  }
  fa0 = ldA(0, 0, 0); fa1 = ldA(0, 0, 1);
  fa2 = ldA(0, 1, 0); fa3 = ldA(0, 1, 1);

  auto body = [&](int t, int c, bf16x8 (&bqc)[4][2], bf16x8 (&bqn)[4][2]) {
#pragma unroll
    for (int q = 0; q < 4; ++q) {
      // --- staging + counted vmcnt (identical to verified round 11) ---
      if (q == 0 && t + 1 < NT) stageA(0, c ^ 1, t + 1);
      if (q == 1 && t + 1 < NT) {
        stageA(1, c ^ 1, t + 1);
        WAIT_VM(4);    // drain own B(t+1); q1's pre-MFMA barrier publishes it
      }
      if (q == 2 && t + 2 < NT) stageB(0, c, t + 2);
      if (q == 3) {
        if (t + 2 < NT) { stageB(1, c, t + 2); WAIT_VM(4); }  // A(t+1) drained
        else            { WAIT_VM(0); }                        // tail drain
      }
      BARRIER();
      WAIT_LGKM0();   // drains reads issued in PREVIOUS phase's tail (cheap now)
      __builtin_amdgcn_s_setprio(1);
      // ksub-outer: 8 independent accs per ksub -> no dependent MFMA pairs
#pragma unroll
      for (int n = 0; n < 4; ++n) {
        acc[2 * q][n]     = __builtin_amdgcn_mfma_f32_16x16x32_bf16(bqc[n][0], fa0, acc[2 * q][n],     0, 0, 0);
        acc[2 * q + 1][n] = __builtin_amdgcn_mfma_f32_16x16x32_bf16(bqc[n][0], fa2, acc[2 * q + 1][n], 0, 0, 0);
      }
#pragma unroll
      for (int n = 0; n < 4; ++n) {
        acc[2 * q][n]     = __builtin_amdgcn_mfma_f32_16x16x32_bf16(bqc[n][1], fa1, acc[2 * q][n],     0, 0, 0);
        acc[2 * q + 1][n] = __builtin_amdgcn_mfma_f32_16x16x32_bf16(bqc[n][1], fa3, acc[2 * q + 1][n], 0, 0, 0);
      }
      __builtin_amdgcn_s_setprio(0);
      // --- tail reads for the NEXT phase (publication-safe, see header) ---
      if (q < 3) {
        fa0 = ldA(c, 2 * (q + 1), 0); fa1 = ldA(c, 2 * (q + 1), 1);
        fa2 = ldA(c, 2 * (q + 1) + 1, 0); fa3 = ldA(c, 2 * (q + 1) + 1, 1);
      } else if (t + 1 < NT) {
        // next tile's q0 frags: A(t+1) published at q3's open barrier
        fa0 = ldA(c ^ 1, 0, 0); fa1 = ldA(c ^ 1, 0, 1);
        fa2 = ldA(c ^ 1, 1, 0); fa3 = ldA(c ^ 1, 1, 1);
      }
      if (q == 2 && t + 1 < NT) {   // B(t+1) published at q1's open barrier
        bqn[0][0] = ldB(c ^ 1, 0, 0); bqn[0][1] = ldB(c ^ 1, 0, 1);
        bqn[1][0] = ldB(c ^ 1, 1, 0); bqn[1][1] = ldB(c ^ 1, 1, 1);
      }
      if (q == 3 && t + 1 < NT) {
        bqn[2][0] = ldB(c ^ 1, 2, 0); bqn[2][1] = ldB(c ^ 1, 2, 1);
        bqn[3][0] = ldB(c ^ 1, 3, 0); bqn[3][1] = ldB(c ^ 1, 3, 1);
      }
      BARRIER();
    }
  };

  for (int tt = 0; tt < NT; tt += 2) {
    body(tt,     0, bqX, bqY);   // uses bqX, prefetches tile tt+1 B -> bqY
    body(tt + 1, 1, bqY, bqX);   // uses bqY, prefetches tile tt+2 B -> bqX
  }

  // epilogue (swapped-D layout, verified rounds 5/6/11): M-sub = fr, N-sub = g*4+j.
  f32x4 biasv[4];
#pragma unroll
  for (int n = 0; n < 4; ++n)
    biasv[n] = *(const f32x4*)&bias[n0 + wn * 64 + n * 16 + g * 4];
#pragma unroll
  for (int m = 0; m < 8; ++m) {
    float* rowp = Y + (size_t)(m0 + wm * 128 + m * 16 + fr) * N_TOT;
#pragma unroll
    for (int n = 0; n < 4; ++n) {
      f32x4 v = acc[m][n] + biasv[n];
      *(f32x4*)&rowp[n0 + wn * 64 + n * 16 + g * 4] = v;
    }
  }
}

// ---------------------------------------------------------------------------
// Fallback GEMM (verified round 1): 128^2 tile, in-kernel fp32->bf16 A staging.
// ---------------------------------------------------------------------------
__global__ __launch_bounds__(256, 2) void gemm_fb_kernel(
    const float* __restrict__ X, const unsigned short* __restrict__ W,
    const float* __restrict__ bias, float* __restrict__ Y) {
  __shared__ __align__(16) unsigned short Alds[2][128 * 32];
  __shared__ __align__(16) unsigned short Blds[2][128 * 32];
  const int tid = threadIdx.x;
  const int lane = tid & 63;
  const int wid = tid >> 6;
  const int wm = wid >> 1, wn = wid & 1;
  int bid = blockIdx.x;
  int wgid = (bid & 7) * (2048 / 8) + (bid >> 3);
  const int m0 = (wgid >> 4) * 128, n0 = (wgid & 15) * 128;
  const int ar = tid >> 3, ac = (tid & 7) * 4;
  const int br = (tid >> 2), bc = (tid & 3) * 8;
  f32x4 acc[4][4];
#pragma unroll
  for (int m = 0; m < 4; ++m)
#pragma unroll
    for (int n = 0; n < 4; ++n) acc[m][n] = {0.f, 0.f, 0.f, 0.f};
  f32x4 apre[4];
  auto stA_l = [&](int k0) {
#pragma unroll
    for (int p = 0; p < 4; ++p)
      apre[p] = *(const f32x4*)&X[(size_t)(m0 + p * 32 + ar) * K_TOT + k0 + ac];
  };
  auto stA_w = [&](int buf) {
#pragma unroll
    for (int p = 0; p < 4; ++p) {
      us4 h;
      h[0] = f2bf(apre[p][0]); h[1] = f2bf(apre[p][1]);
      h[2] = f2bf(apre[p][2]); h[3] = f2bf(apre[p][3]);
      *(us4*)&Alds[buf][(p * 32 + ar) * 32 + ac] = h;
    }
  };
  auto stB = [&](int k0, int buf) {
#pragma unroll
    for (int i = 0; i < 2; ++i)
      gld_lds16(&W[(size_t)(n0 + i * 64 + br) * K_TOT + k0 + bc],
                &Blds[buf][i * 2048 + wid * 512]);
  };
  auto comp = [&](int buf) {
    const unsigned short* Ab = &Alds[buf][(wm * 64 + (lane & 15)) * 32 + (lane >> 4) * 8];
    const unsigned short* Bb = &Blds[buf][(wn * 64 + (lane & 15)) * 32 + (lane >> 4) * 8];
    bf16x8 af[4], bfv[4];
#pragma unroll
    for (int m = 0; m < 4; ++m) af[m] = *(const bf16x8*)(Ab + m * 16 * 32);
#pragma unroll
    for (int n = 0; n < 4; ++n) bfv[n] = *(const bf16x8*)(Bb + n * 16 * 32);
#pragma unroll
    for (int m = 0; m < 4; ++m)
#pragma unroll
      for (int n = 0; n < 4; ++n)
        acc[m][n] = __builtin_amdgcn_mfma_f32_16x16x32_bf16(af[m], bfv[n], acc[m][n], 0, 0, 0);
  };
  stA_l(0); stB(0, 0); stA_w(0);
  __syncthreads();
  for (int kt = 0; kt < 64; ++kt) {
    const int cur = kt & 1, nxt = cur ^ 1;
    if (kt + 1 < 64) { stA_l((kt + 1) * 32); stB((kt + 1) * 32, nxt); }
    comp(cur);
    if (kt + 1 < 64) stA_w(nxt);
    __syncthreads();
  }
  const int col = lane & 15, rb = (lane >> 4) * 4;
#pragma unroll
  for (int n = 0; n < 4; ++n) {
    const int gc = n0 + wn * 64 + n * 16 + col;
    const float bv = bias[gc];
#pragma unroll
    for (int m = 0; m < 4; ++m)
#pragma unroll
      for (int j = 0; j < 4; ++j)
        Y[(size_t)(m0 + wm * 64 + m * 16 + rb + j) * N_TOT + gc] = acc[m][n][j] + bv;
  }
}

extern "C" void kernel_launch(void* const* d_in, const int* in_sizes, int n_in,
                              void* d_out, int out_size, void* d_ws, size_t ws_size,
                              hipStream_t stream) {
  const float* x    = (const float*)d_in[0];
  const float* c1   = (const float*)d_in[1];
  const float* c2   = (const float*)d_in[2];
  const float* bias = (const float*)d_in[3];
  float* y          = (float*)d_out;
  unsigned short* W = (unsigned short*)d_ws;                        // 8 MB
  unsigned short* Xb = (unsigned short*)((char*)d_ws + (8u << 20)); // 64 MB

  const size_t need = (size_t)(8u << 20) + (size_t)M_TOT * K_TOT * 2;
  if (ws_size >= need) {
    prep_kernel<<<16384 + 16384, 256, 0, stream>>>(x, Xb, c1, c2, W, 16384);
    gemm8p_kernel<<<(M_TOT / 256) * (N_TOT / 256), 512, 0, stream>>>(Xb, W, bias, y);
  } else {
    prep_kernel<<<16384, 256, 0, stream>>>(x, nullptr, c1, c2, W, 0);  // W only
    gemm_fb_kernel<<<(M_TOT / 128) * (N_TOT / 128), 256, 0, stream>>>(x, W, bias, y);
  }
}